// Round 1
// baseline (1821.097 us; speedup 1.0000x reference)
//
#include <hip/hip_runtime.h>

typedef _Float16 f16;
typedef __attribute__((ext_vector_type(8))) _Float16 f16x8;
typedef __attribute__((ext_vector_type(4))) float f32x4;

#define HD 512
#define NBSEQ 256
#define LSEQ 256
#define PREDN 96

// ---------------------------------------------------------------------------
// prep_swizzle: repack Wxh and Whh into MFMA B-fragment order, f16.
// Per table layout: [kk(16)][nt(32)][lane(64)][j(8)], value = W[n][k] with
//   n = nt*16 + (lane&15)   (output column of y = x @ W^T)
//   k = kk*32 + (lane>>4)*8 + j
// so each MFMA B-frag is one contiguous 16B-per-lane (1KB/wave) load.
// Table 0 = Wxh (262144 f16), table 1 = Whh (at +262144 elements).
// ---------------------------------------------------------------------------
__global__ __launch_bounds__(512) void prep_swizzle(const float* __restrict__ Wxh,
                                                    const float* __restrict__ Whh,
                                                    f16* __restrict__ bs) {
    int gid = blockIdx.x * 512 + threadIdx.x;   // 0..65535
    int table = gid >> 15;
    int rem = gid & 32767;
    int kk = rem >> 11;
    int nt = (rem >> 6) & 31;
    int l = rem & 63;
    int n = nt * 16 + (l & 15);
    int k = kk * 32 + (l >> 4) * 8;
    const float* W = (table ? Whh : Wxh) + (size_t)n * HD + k;
    f16x8 v;
#pragma unroll
    for (int j = 0; j < 8; j++) v[j] = (f16)W[j];
    *reinterpret_cast<f16x8*>(bs + (size_t)gid * 8) = v;
}

// ---------------------------------------------------------------------------
// gemm_xw: xW = x @ Wxh^T, [65536,512] @ [512,512] -> fp32, written IN-PLACE
// into the rec region of d_out (xW[s,l] is consumed and overwritten by h[s,l]
// at step l of rec_fused -> no workspace needed).
// 512 WGs x 512 thr (8 waves). Per WG: 128 rows x 512 cols, K=512.
// Wave w owns cols [w*64, w*64+64). Double-buffered LDS, 1 barrier/K-step.
// ---------------------------------------------------------------------------
__global__ __launch_bounds__(512, 2) void gemm_xw(const float* __restrict__ x,
                                                  const f16* __restrict__ bsw,
                                                  float* __restrict__ xw) {
    __shared__ f16 Al[2][128][40];   // A tile, row stride 40 f16 (80B) -> 2-way banks
    __shared__ f16 Bl[2][16384];     // B K-chunk in frag order: [nt(32)][lane(64)][8]
    const int tid = threadIdx.x;
    const int w = tid >> 6, l = tid & 63;
    const size_t r0 = (size_t)blockIdx.x * 128;

    f32x4 acc[8][4];
#pragma unroll
    for (int mt = 0; mt < 8; mt++)
#pragma unroll
        for (int nt = 0; nt < 4; nt++) acc[mt][nt] = (f32x4)0.f;

    const int arow_l = l & 15;
    const int akc = (l >> 4) * 8;
    const int srow = tid >> 2, sc8 = (tid & 3) * 8;

    for (int kk = 0; kk < 16; kk++) {
        const int buf = kk & 1;
        // stage A: 128 rows x 32 k of x, fp32 -> f16
        {
            const float* src = x + (r0 + srow) * HD + kk * 32 + sc8;
            float4 f0 = *reinterpret_cast<const float4*>(src);
            float4 f1 = *reinterpret_cast<const float4*>(src + 4);
            f16x8 a;
            a[0] = (f16)f0.x; a[1] = (f16)f0.y; a[2] = (f16)f0.z; a[3] = (f16)f0.w;
            a[4] = (f16)f1.x; a[5] = (f16)f1.y; a[6] = (f16)f1.z; a[7] = (f16)f1.w;
            *reinterpret_cast<f16x8*>(&Al[buf][srow][sc8]) = a;
        }
        // stage B: 32KB of pre-swizzled Wxh (layout already matches frag reads)
        {
            const f16* bsrc = bsw + (size_t)kk * 16384 + tid * 8;
#pragma unroll
            for (int i = 0; i < 4; i++)
                *reinterpret_cast<f16x8*>(&Bl[buf][i * 4096 + tid * 8]) =
                    *reinterpret_cast<const f16x8*>(bsrc + i * 4096);
        }
        __syncthreads();   // single barrier per K-step (dbuf makes WAR safe)

        f16x8 af[8];
#pragma unroll
        for (int mt = 0; mt < 8; mt++)
            af[mt] = *reinterpret_cast<const f16x8*>(&Al[buf][mt * 16 + arow_l][akc]);
#pragma unroll
        for (int nt = 0; nt < 4; nt++) {
            f16x8 bf = *reinterpret_cast<const f16x8*>(&Bl[buf][((w * 4 + nt) * 64 + l) * 8]);
#pragma unroll
            for (int mt = 0; mt < 8; mt++)
                acc[mt][nt] = __builtin_amdgcn_mfma_f32_16x16x32_f16(af[mt], bf, acc[mt][nt], 0, 0, 0);
        }
    }

    // epilogue: C layout (16x16): col = lane&15, row = (lane>>4)*4 + reg
#pragma unroll
    for (int mt = 0; mt < 8; mt++)
#pragma unroll
        for (int nt = 0; nt < 4; nt++)
#pragma unroll
            for (int r = 0; r < 4; r++) {
                size_t row = r0 + mt * 16 + (l >> 4) * 4 + r;
                int col = w * 64 + nt * 16 + arow_l;
                xw[row * HD + col] = acc[mt][nt][r];
            }
}

// ---------------------------------------------------------------------------
// rec_fused: persistent recurrence + prediction + LayerNorm.
// 16 WGs x 512 thr (8 waves). WG sg owns sequences [sg*16, sg*16+16) = M=16.
// h[16][512] f16 double-buffered in LDS (row stride 520 f16 -> conflict-free).
// Per step: acc = h @ Whh^T via 64 MFMA/wave, B-frags streamed from the
// pre-swizzled table in L2 (2 WGs/XCD -> plenty of L2 BW). xW loads are
// issued before the K-loop and added in the epilogue (latency hidden).
// Pred steps (t>=256): no xW; LayerNorm fused from the LDS h, written to outs.
// ---------------------------------------------------------------------------
__global__ __launch_bounds__(512, 2) void rec_fused(const float* __restrict__ gamma,
                                                    const float* __restrict__ beta,
                                                    const f16* __restrict__ bsw,
                                                    float* __restrict__ out) {
    __shared__ f16 hb[2][16][520];
    __shared__ float gl[HD], bl[HD];
    const int tid = threadIdx.x;
    const int w = tid >> 6, l = tid & 63;
    const int sg = blockIdx.x;

    gl[tid] = gamma[tid];
    bl[tid] = beta[tid];
    {
        f16* hp = &hb[0][0][0];
        for (int i = tid; i < 16 * 520; i += 512) {
            hp[i] = (f16)0.f;
            hp[16 * 520 + i] = (f16)0.f;
        }
    }
    __syncthreads();

    float* rec = out;
    float* outs = out + (size_t)NBSEQ * LSEQ * HD;
    const f16* bbase = bsw + l * 8;
    const int arow = l & 15;
    const int ak = (l >> 4) * 8;
    const int ln_r = tid >> 5, ln_q = tid & 31;
    int cur = 0;

    for (int t = 0; t < LSEQ + PREDN; t++) {
        const bool is_rec = (t < LSEQ);

        // xW preload (issued early; consumed only in epilogue)
        float xwv[4][4];
        if (is_rec) {
#pragma unroll
            for (int nt = 0; nt < 4; nt++)
#pragma unroll
                for (int r = 0; r < 4; r++) {
                    int s = sg * 16 + (l >> 4) * 4 + r;
                    int col = w * 64 + nt * 16 + arow;
                    xwv[nt][r] = rec[((size_t)s * LSEQ + t) * HD + col];
                }
        } else {
#pragma unroll
            for (int nt = 0; nt < 4; nt++)
#pragma unroll
                for (int r = 0; r < 4; r++) xwv[nt][r] = 0.f;
        }

        f32x4 acc[4];
#pragma unroll
        for (int nt = 0; nt < 4; nt++) acc[nt] = (f32x4)0.f;

#pragma unroll
        for (int kk = 0; kk < 16; kk++) {
            f16x8 a = *reinterpret_cast<const f16x8*>(&hb[cur][arow][kk * 32 + ak]);
#pragma unroll
            for (int nt = 0; nt < 4; nt++) {
                f16x8 b = *reinterpret_cast<const f16x8*>(bbase + (size_t)(kk * 32 + w * 4 + nt) * 512);
                acc[nt] = __builtin_amdgcn_mfma_f32_16x16x32_f16(a, b, acc[nt], 0, 0, 0);
            }
        }

        const int nxt = cur ^ 1;
#pragma unroll
        for (int nt = 0; nt < 4; nt++)
#pragma unroll
            for (int r = 0; r < 4; r++) {
                int rr = (l >> 4) * 4 + r;
                int col = w * 64 + nt * 16 + arow;
                float hv = acc[nt][r] + xwv[nt][r];
                hb[nxt][rr][col] = (f16)hv;
                if (is_rec) {
                    int s = sg * 16 + rr;
                    rec[((size_t)s * LSEQ + t) * HD + col] = hv;
                }
            }
        __syncthreads();

        if (!is_rec) {
            // fused LayerNorm of this pred step's h -> outs[t-256]
            const int pt = t - LSEQ;
            float v[16], sum = 0.f, sq = 0.f;
#pragma unroll
            for (int k = 0; k < 16; k++) {
                v[k] = (float)hb[nxt][ln_r][ln_q * 16 + k];
                sum += v[k];
                sq += v[k] * v[k];
            }
#pragma unroll
            for (int m = 16; m >= 1; m >>= 1) {
                sum += __shfl_xor(sum, m);
                sq += __shfl_xor(sq, m);
            }
            const float mean = sum * (1.f / 512.f);
            const float var = sq * (1.f / 512.f) - mean * mean;
            const float rstd = rsqrtf(var + 1e-5f);
            const int s = sg * 16 + ln_r;
            float* dst = outs + ((size_t)s * PREDN + pt) * HD + ln_q * 16;
#pragma unroll
            for (int k = 0; k < 16; k++) {
                int c = ln_q * 16 + k;
                dst[k] = (v[k] - mean) * rstd * gl[c] + bl[c];
            }
            // Safe: LN only READS hb[nxt]; next step writes hb[cur(old)] and is
            // fenced by the next __syncthreads before anyone touches hb[nxt].
        }
        cur = nxt;
    }
}

extern "C" void kernel_launch(void* const* d_in, const int* in_sizes, int n_in,
                              void* d_out, int out_size, void* d_ws, size_t ws_size,
                              hipStream_t stream) {
    (void)in_sizes; (void)n_in; (void)out_size; (void)ws_size;
    const float* x     = (const float*)d_in[0];
    const float* Wxh   = (const float*)d_in[1];
    const float* Whh   = (const float*)d_in[2];
    const float* gamma = (const float*)d_in[3];
    const float* beta  = (const float*)d_in[4];
    // d_in[5] = pred_len, fixed at 96 by setup_inputs (grid must be static anyway)
    float* out = (float*)d_out;
    f16* bs = (f16*)d_ws;                    // [0]: Wxh swizzled, [+262144]: Whh swizzled (1MB total)

    hipLaunchKernelGGL(prep_swizzle, dim3(128), dim3(512), 0, stream, Wxh, Whh, bs);
    hipLaunchKernelGGL(gemm_xw, dim3(512), dim3(512), 0, stream, x, bs, out);
    hipLaunchKernelGGL(rec_fused, dim3(16), dim3(512), 0, stream, gamma, beta, bs + 262144, out);
}

// Round 2
// 894.923 us; speedup vs baseline: 2.0349x; 2.0349x over previous
//
#include <hip/hip_runtime.h>

typedef _Float16 f16;
typedef __attribute__((ext_vector_type(8))) _Float16 f16x8;
typedef __attribute__((ext_vector_type(4))) float f32x4;

#define HD 512
#define NBSEQ 256
#define LSEQ 256
#define PREDN 96
#define SLOT 262144   // f16 elements per 512x512 matrix

// ws layout (f16):
//   [0]                : TX  = Wxh swizzled (B-frag form of y = x@Wxh^T)
//   [SLOT*k], k=1..96  : T[k] = swizzled form of A^k  (A = Whh^T)
//   [SLOT*(97+j)]      : R[2^j] row-major f16, j=0..6 (A^1,A^2,...,A^64)
//   [SLOT*104]         : Hbuf [16][256][512] f16 (chunk-end states H_c)
// total = 58,720,256 bytes of d_ws.

// T-form of M: T(kk,nt,lane,j) = M[k][n], k=kk*32+(lane>>4)*8+j, n=nt*16+(lane&15)
// -> each MFMA B-frag = one contiguous f16x8 per lane.

// ---------------------------------------------------------------------------
// prep: TX (Wxh swizzled), T[1] (Whh swizzled), R[1] = A row-major (Whh^T).
// ---------------------------------------------------------------------------
__global__ __launch_bounds__(512) void prep(const float* __restrict__ Wxh,
                                            const float* __restrict__ Whh,
                                            f16* __restrict__ ws) {
    int gid = blockIdx.x * 512 + threadIdx.x;     // grid 192 -> gid < 98304
    if (gid < 65536) {
        int table = gid >> 15;
        int rem = gid & 32767;
        int kk = rem >> 11;
        int nt = (rem >> 6) & 31;
        int l = rem & 63;
        int n = nt * 16 + (l & 15);
        int k = kk * 32 + (l >> 4) * 8;
        const float* W = (table ? Whh : Wxh) + (size_t)n * HD + k;
        f16x8 v;
#pragma unroll
        for (int j = 0; j < 8; j++) v[j] = (f16)W[j];
        *reinterpret_cast<f16x8*>(ws + (size_t)gid * 8) = v;
    } else {
        int idx = gid - 65536;                    // 0..32767
        int m = idx >> 6, kc = (idx & 63) * 8;
        f16* R1 = ws + (size_t)SLOT * 97;
        f16x8 v;
#pragma unroll
        for (int j = 0; j < 8; j++) v[j] = (f16)Whh[(size_t)(kc + j) * HD + m];  // A[m][k]=Whh[k][m]
        *reinterpret_cast<f16x8*>(R1 + (size_t)m * HD + kc) = v;
    }
}

// ---------------------------------------------------------------------------
// gemm_xw: xW = x @ Wxh^T  [65536,512]@[512,512] -> fp32, in-place into rec.
// (verified in R1)
// ---------------------------------------------------------------------------
__global__ __launch_bounds__(512, 2) void gemm_xw(const float* __restrict__ x,
                                                  const f16* __restrict__ bsw,
                                                  float* __restrict__ xw) {
    __shared__ f16 Al[2][128][40];
    __shared__ f16 Bl[2][16384];
    const int tid = threadIdx.x;
    const int w = tid >> 6, l = tid & 63;
    const size_t r0 = (size_t)blockIdx.x * 128;

    f32x4 acc[8][4];
#pragma unroll
    for (int mt = 0; mt < 8; mt++)
#pragma unroll
        for (int nt = 0; nt < 4; nt++) acc[mt][nt] = (f32x4)0.f;

    const int arow_l = l & 15;
    const int akc = (l >> 4) * 8;
    const int srow = tid >> 2, sc8 = (tid & 3) * 8;

    for (int kk = 0; kk < 16; kk++) {
        const int buf = kk & 1;
        {
            const float* src = x + (r0 + srow) * HD + kk * 32 + sc8;
            float4 f0 = *reinterpret_cast<const float4*>(src);
            float4 f1 = *reinterpret_cast<const float4*>(src + 4);
            f16x8 a;
            a[0] = (f16)f0.x; a[1] = (f16)f0.y; a[2] = (f16)f0.z; a[3] = (f16)f0.w;
            a[4] = (f16)f1.x; a[5] = (f16)f1.y; a[6] = (f16)f1.z; a[7] = (f16)f1.w;
            *reinterpret_cast<f16x8*>(&Al[buf][srow][sc8]) = a;
        }
        {
            const f16* bsrc = bsw + (size_t)kk * 16384 + tid * 8;
#pragma unroll
            for (int i = 0; i < 4; i++)
                *reinterpret_cast<f16x8*>(&Bl[buf][i * 4096 + tid * 8]) =
                    *reinterpret_cast<const f16x8*>(bsrc + i * 4096);
        }
        __syncthreads();

        f16x8 af[8];
#pragma unroll
        for (int mt = 0; mt < 8; mt++)
            af[mt] = *reinterpret_cast<const f16x8*>(&Al[buf][mt * 16 + arow_l][akc]);
#pragma unroll
        for (int nt = 0; nt < 4; nt++) {
            f16x8 bf = *reinterpret_cast<const f16x8*>(&Bl[buf][((w * 4 + nt) * 64 + l) * 8]);
#pragma unroll
            for (int mt = 0; mt < 8; mt++)
                acc[mt][nt] = __builtin_amdgcn_mfma_f32_16x16x32_f16(af[mt], bf, acc[mt][nt], 0, 0, 0);
        }
    }
#pragma unroll
    for (int mt = 0; mt < 8; mt++)
#pragma unroll
        for (int nt = 0; nt < 4; nt++)
#pragma unroll
            for (int r = 0; r < 4; r++) {
                size_t row = r0 + mt * 16 + (l >> 4) * 4 + r;
                int col = w * 64 + nt * 16 + arow_l;
                xw[row * HD + col] = acc[mt][nt][r];
            }
}

// ---------------------------------------------------------------------------
// core128: C[128,512] = A[128,512](f16 row-major) @ Y(T-form), K=512.
// 8 waves N-split 64; A staged to LDS dbuf, B-frags direct from L2.
// ---------------------------------------------------------------------------
__device__ __forceinline__ void core128(const f16* __restrict__ Asrc,
                                        const f16* __restrict__ Y,
                                        f16 (*Al)[128][40],
                                        f32x4 (*acc)[4], int tid) {
    const int w = tid >> 6, l = tid & 63;
    const int srow = tid >> 2, sc8 = (tid & 3) * 8;
    const int arow = l & 15, ak = (l >> 4) * 8;
    for (int kk = 0; kk < 16; kk++) {
        const int buf = kk & 1;
        *reinterpret_cast<f16x8*>(&Al[buf][srow][sc8]) =
            *reinterpret_cast<const f16x8*>(Asrc + (size_t)srow * HD + kk * 32 + sc8);
        __syncthreads();
        f16x8 af[8];
#pragma unroll
        for (int mt = 0; mt < 8; mt++)
            af[mt] = *reinterpret_cast<const f16x8*>(&Al[buf][mt * 16 + arow][ak]);
#pragma unroll
        for (int nt = 0; nt < 4; nt++) {
            f16x8 b = *reinterpret_cast<const f16x8*>(Y + (size_t)(kk * 32 + w * 4 + nt) * 512 + l * 8);
#pragma unroll
            for (int mt = 0; mt < 8; mt++)
                acc[mt][nt] = __builtin_amdgcn_mfma_f32_16x16x32_f16(af[mt], b, acc[mt][nt], 0, 0, 0);
        }
    }
}

// ---------------------------------------------------------------------------
// powlevel: doubling level h. block bx: j0=bx>>2 (output index), mtile=bx&3.
// Computes A^(h+1+j0) = R[h] @ T[1+j0]; writes T-form (+ R row-major when
// output == A^(2h), i.e. 1+j0==h).
// ---------------------------------------------------------------------------
__global__ __launch_bounds__(512, 2) void powlevel(const f16* __restrict__ RX,
                                                   f16* __restrict__ ws,
                                                   f16* __restrict__ Rsq,
                                                   int h) {
    __shared__ f16 Al[2][128][40];
    const int tid = threadIdx.x;
    const int j0 = blockIdx.x >> 2, mtile = blockIdx.x & 3;
    const int m0 = mtile * 128;
    const f16* Y = ws + (size_t)SLOT * (1 + j0);
    f16* Tout = ws + (size_t)SLOT * (h + 1 + j0);

    f32x4 acc[8][4];
#pragma unroll
    for (int mt = 0; mt < 8; mt++)
#pragma unroll
        for (int nt = 0; nt < 4; nt++) acc[mt][nt] = (f32x4)0.f;

    core128(RX + (size_t)m0 * HD, Y, Al, acc, tid);

    const int w = tid >> 6, l = tid & 63;
    const bool doR = (1 + j0) == h;
#pragma unroll
    for (int mt = 0; mt < 8; mt++)
#pragma unroll
        for (int nt = 0; nt < 4; nt++)
#pragma unroll
            for (int r = 0; r < 4; r++) {
                int m = m0 + mt * 16 + (l >> 4) * 4 + r;
                int n = w * 64 + nt * 16 + (l & 15);
                f16 v = (f16)acc[mt][nt][r];
                size_t tix = (((size_t)(m >> 5) * 32 + (n >> 4)) * 64 +
                              (((m >> 3) & 3) * 16 + (n & 15))) * 8 + (m & 7);
                Tout[tix] = v;
                if (doR) Rsq[(size_t)m * HD + n] = v;
            }
}

// ---------------------------------------------------------------------------
// phaseA: local prefixes. 128 WGs = 16 chunks x 8 seq-groups (M=32).
// L_i = L_{i-1} @ A + xW_i, written f32 in-place into rec (over xW).
// ---------------------------------------------------------------------------
__global__ __launch_bounds__(512, 2) void phaseA(float* __restrict__ rec,
                                                 const f16* __restrict__ T1) {
    __shared__ f16 hb[2][32][520];
    const int tid = threadIdx.x, w = tid >> 6, l = tid & 63;
    const int c = blockIdx.x >> 3, sg = blockIdx.x & 7;
    const int s0 = sg * 32;
    {
        f16* hp = &hb[0][0][0];
        for (int i = tid; i < 32 * 520; i += 512) hp[i] = (f16)0.f;
    }
    __syncthreads();
    const int arow = l & 15, ak = (l >> 4) * 8;
    int cur = 0;
    for (int i = 0; i < 16; i++) {
        const int t = c * 16 + i;
        float xwv[2][4][4];
#pragma unroll
        for (int mt = 0; mt < 2; mt++)
#pragma unroll
            for (int nt = 0; nt < 4; nt++)
#pragma unroll
                for (int r = 0; r < 4; r++) {
                    int s = s0 + mt * 16 + (l >> 4) * 4 + r;
                    int col = w * 64 + nt * 16 + arow;
                    xwv[mt][nt][r] = rec[((size_t)s * LSEQ + t) * HD + col];
                }
        f32x4 acc[2][4];
#pragma unroll
        for (int mt = 0; mt < 2; mt++)
#pragma unroll
            for (int nt = 0; nt < 4; nt++) acc[mt][nt] = (f32x4)0.f;

#pragma unroll
        for (int kk = 0; kk < 16; kk++) {
            f16x8 a0 = *reinterpret_cast<const f16x8*>(&hb[cur][arow][kk * 32 + ak]);
            f16x8 a1 = *reinterpret_cast<const f16x8*>(&hb[cur][16 + arow][kk * 32 + ak]);
#pragma unroll
            for (int nt = 0; nt < 4; nt++) {
                f16x8 b = *reinterpret_cast<const f16x8*>(T1 + (size_t)(kk * 32 + w * 4 + nt) * 512 + l * 8);
                acc[0][nt] = __builtin_amdgcn_mfma_f32_16x16x32_f16(a0, b, acc[0][nt], 0, 0, 0);
                acc[1][nt] = __builtin_amdgcn_mfma_f32_16x16x32_f16(a1, b, acc[1][nt], 0, 0, 0);
            }
        }
        const int nxt = cur ^ 1;
#pragma unroll
        for (int mt = 0; mt < 2; mt++)
#pragma unroll
            for (int nt = 0; nt < 4; nt++)
#pragma unroll
                for (int r = 0; r < 4; r++) {
                    int rr = mt * 16 + (l >> 4) * 4 + r;
                    int col = w * 64 + nt * 16 + arow;
                    float hv = acc[mt][nt][r] + xwv[mt][nt][r];
                    hb[nxt][rr][col] = (f16)hv;
                    int s = s0 + rr;
                    rec[((size_t)s * LSEQ + t) * HD + col] = hv;
                }
        __syncthreads();
        cur = nxt;
    }
}

// ---------------------------------------------------------------------------
// phaseB: chunk carries. 16 WGs (M=16 seqs). H_c = H_{c-1}@A^16 + L_{c,15}.
// Writes H_c: f32 into rec[t=16c+15], f16 into Hbuf[c].
// ---------------------------------------------------------------------------
__global__ __launch_bounds__(512, 2) void phaseB(float* __restrict__ rec,
                                                 const f16* __restrict__ T16,
                                                 f16* __restrict__ Hb) {
    __shared__ f16 hb[2][16][520];
    const int tid = threadIdx.x, w = tid >> 6, l = tid & 63;
    const int s0 = blockIdx.x * 16;
    const int arow = l & 15, ak = (l >> 4) * 8;

    // c = 0: H_0 = L_{0,15} (already in rec)
#pragma unroll
    for (int nt = 0; nt < 4; nt++)
#pragma unroll
        for (int r = 0; r < 4; r++) {
            int rr = (l >> 4) * 4 + r;
            int col = w * 64 + nt * 16 + arow;
            int s = s0 + rr;
            float v = rec[((size_t)s * LSEQ + 15) * HD + col];
            hb[0][rr][col] = (f16)v;
            Hb[(size_t)s * HD + col] = (f16)v;
        }
    __syncthreads();
    int cur = 0;
    for (int c = 1; c < 16; c++) {
        const int t = c * 16 + 15;
        float Lv[4][4];
#pragma unroll
        for (int nt = 0; nt < 4; nt++)
#pragma unroll
            for (int r = 0; r < 4; r++) {
                int s = s0 + (l >> 4) * 4 + r;
                int col = w * 64 + nt * 16 + arow;
                Lv[nt][r] = rec[((size_t)s * LSEQ + t) * HD + col];
            }
        f32x4 acc[4];
#pragma unroll
        for (int nt = 0; nt < 4; nt++) acc[nt] = (f32x4)0.f;
#pragma unroll
        for (int kk = 0; kk < 16; kk++) {
            f16x8 a = *reinterpret_cast<const f16x8*>(&hb[cur][arow][kk * 32 + ak]);
#pragma unroll
            for (int nt = 0; nt < 4; nt++) {
                f16x8 b = *reinterpret_cast<const f16x8*>(T16 + (size_t)(kk * 32 + w * 4 + nt) * 512 + l * 8);
                acc[nt] = __builtin_amdgcn_mfma_f32_16x16x32_f16(a, b, acc[nt], 0, 0, 0);
            }
        }
        const int nxt = cur ^ 1;
#pragma unroll
        for (int nt = 0; nt < 4; nt++)
#pragma unroll
            for (int r = 0; r < 4; r++) {
                int rr = (l >> 4) * 4 + r;
                int col = w * 64 + nt * 16 + arow;
                float hv = acc[nt][r] + Lv[nt][r];
                hb[nxt][rr][col] = (f16)hv;
                int s = s0 + rr;
                rec[((size_t)s * LSEQ + t) * HD + col] = hv;
                Hb[((size_t)c * NBSEQ + s) * HD + col] = (f16)hv;
            }
        __syncthreads();
        cur = nxt;
    }
}

// ---------------------------------------------------------------------------
// phaseC: fill-in. 450 WGs: p=bx>>1 -> i=p/15 (0..14), c=1+p%15; half=bx&1.
// rec[s, 16c+i] += Hbuf[c-1] @ A^(i+1).  (i-major order: 30 consecutive
// blocks share the same T matrix for L2 locality.)
// ---------------------------------------------------------------------------
__global__ __launch_bounds__(512, 2) void phaseC(float* __restrict__ rec,
                                                 const f16* __restrict__ ws,
                                                 const f16* __restrict__ Hb) {
    __shared__ f16 Al[2][128][40];
    const int tid = threadIdx.x;
    const int p = blockIdx.x >> 1, half = blockIdx.x & 1;
    const int i = p / 15, c = 1 + p % 15;
    const int m0 = half * 128;
    const f16* Y = ws + (size_t)SLOT * (i + 1);
    const f16* Asrc = Hb + ((size_t)(c - 1) * NBSEQ + m0) * HD;

    f32x4 acc[8][4];
#pragma unroll
    for (int mt = 0; mt < 8; mt++)
#pragma unroll
        for (int nt = 0; nt < 4; nt++) acc[mt][nt] = (f32x4)0.f;

    core128(Asrc, Y, Al, acc, tid);

    const int w = tid >> 6, l = tid & 63;
    const int t = c * 16 + i;
#pragma unroll
    for (int mt = 0; mt < 8; mt++)
#pragma unroll
        for (int nt = 0; nt < 4; nt++)
#pragma unroll
            for (int r = 0; r < 4; r++) {
                int s = m0 + mt * 16 + (l >> 4) * 4 + r;
                int col = w * 64 + nt * 16 + (l & 15);
                size_t a = ((size_t)s * LSEQ + t) * HD + col;
                rec[a] += acc[mt][nt][r];
            }
}

// ---------------------------------------------------------------------------
// predLN: outs[s, t-1] = LN(H_15 @ A^t), t=1..96. 192 WGs (96 t x 2 halves).
// LN fused: per-row stats via intra-wave shuffles + cross-wave LDS partials.
// ---------------------------------------------------------------------------
__global__ __launch_bounds__(512, 2) void predLN(const float* __restrict__ gamma,
                                                 const float* __restrict__ beta,
                                                 const f16* __restrict__ ws,
                                                 const f16* __restrict__ Hb,
                                                 float* __restrict__ outs) {
    __shared__ f16 Al[2][128][40];
    __shared__ float psum[8][128], psq[8][128], gl[HD], bl[HD];
    const int tid = threadIdx.x;
    const int t = 1 + (blockIdx.x >> 1), half = blockIdx.x & 1;
    const int m0 = half * 128;
    gl[tid] = gamma[tid];
    bl[tid] = beta[tid];

    f32x4 acc[8][4];
#pragma unroll
    for (int mt = 0; mt < 8; mt++)
#pragma unroll
        for (int nt = 0; nt < 4; nt++) acc[mt][nt] = (f32x4)0.f;

    core128(Hb + ((size_t)15 * NBSEQ + m0) * HD, ws + (size_t)SLOT * t, Al, acc, tid);

    const int w = tid >> 6, l = tid & 63;
#pragma unroll
    for (int mt = 0; mt < 8; mt++)
#pragma unroll
        for (int r = 0; r < 4; r++) {
            int rloc = mt * 16 + (l >> 4) * 4 + r;
            float s1 = 0.f, s2 = 0.f;
#pragma unroll
            for (int nt = 0; nt < 4; nt++) {
                float v = acc[mt][nt][r];
                s1 += v; s2 += v * v;
            }
#pragma unroll
            for (int m = 8; m >= 1; m >>= 1) {
                s1 += __shfl_xor(s1, m);
                s2 += __shfl_xor(s2, m);
            }
            if ((l & 15) == 0) { psum[w][rloc] = s1; psq[w][rloc] = s2; }
        }
    __syncthreads();
#pragma unroll
    for (int mt = 0; mt < 8; mt++)
#pragma unroll
        for (int r = 0; r < 4; r++) {
            int rloc = mt * 16 + (l >> 4) * 4 + r;
            float tot = 0.f, tq = 0.f;
#pragma unroll
            for (int ww = 0; ww < 8; ww++) { tot += psum[ww][rloc]; tq += psq[ww][rloc]; }
            float mean = tot * (1.f / 512.f);
            float var = tq * (1.f / 512.f) - mean * mean;
            float rstd = rsqrtf(var + 1e-5f);
            int s = m0 + rloc;
#pragma unroll
            for (int nt = 0; nt < 4; nt++) {
                int col = w * 64 + nt * 16 + (l & 15);
                outs[((size_t)s * PREDN + (t - 1)) * HD + col] =
                    (acc[mt][nt][r] - mean) * rstd * gl[col] + bl[col];
            }
        }
}

extern "C" void kernel_launch(void* const* d_in, const int* in_sizes, int n_in,
                              void* d_out, int out_size, void* d_ws, size_t ws_size,
                              hipStream_t stream) {
    (void)in_sizes; (void)n_in; (void)out_size; (void)ws_size;
    const float* x     = (const float*)d_in[0];
    const float* Wxh   = (const float*)d_in[1];
    const float* Whh   = (const float*)d_in[2];
    const float* gamma = (const float*)d_in[3];
    const float* beta  = (const float*)d_in[4];
    float* out = (float*)d_out;
    float* outs = out + (size_t)NBSEQ * LSEQ * HD;
    f16* ws = (f16*)d_ws;                         // needs 56 MB of d_ws

    f16* R[7];
    for (int j = 0; j < 7; j++) R[j] = ws + (size_t)SLOT * (97 + j);
    f16* Hb = ws + (size_t)SLOT * 104;

    hipLaunchKernelGGL(prep, dim3(192), dim3(512), 0, stream, Wxh, Whh, ws);
    hipLaunchKernelGGL(gemm_xw, dim3(512), dim3(512), 0, stream, x, ws, out);
    // powers: T2..T96 by doubling (R[j] = A^(2^j))
    hipLaunchKernelGGL(powlevel, dim3(4),   dim3(512), 0, stream, R[0], ws, R[1], 1);
    hipLaunchKernelGGL(powlevel, dim3(8),   dim3(512), 0, stream, R[1], ws, R[2], 2);
    hipLaunchKernelGGL(powlevel, dim3(16),  dim3(512), 0, stream, R[2], ws, R[3], 4);
    hipLaunchKernelGGL(powlevel, dim3(32),  dim3(512), 0, stream, R[3], ws, R[4], 8);
    hipLaunchKernelGGL(powlevel, dim3(64),  dim3(512), 0, stream, R[4], ws, R[5], 16);
    hipLaunchKernelGGL(powlevel, dim3(128), dim3(512), 0, stream, R[5], ws, R[6], 32);
    hipLaunchKernelGGL(powlevel, dim3(128), dim3(512), 0, stream, R[6], ws, R[6], 64); // no R write (1+j0 != 64)
    hipLaunchKernelGGL(phaseA, dim3(128), dim3(512), 0, stream, out, ws + (size_t)SLOT * 1);
    hipLaunchKernelGGL(phaseB, dim3(16),  dim3(512), 0, stream, out, ws + (size_t)SLOT * 16, Hb);
    hipLaunchKernelGGL(phaseC, dim3(450), dim3(512), 0, stream, out, ws, Hb);
    hipLaunchKernelGGL(predLN, dim3(192), dim3(512), 0, stream, gamma, beta, ws, Hb, outs);
}

// Round 3
// 681.705 us; speedup vs baseline: 2.6714x; 1.3128x over previous
//
#include <hip/hip_runtime.h>

typedef _Float16 f16;
typedef __attribute__((ext_vector_type(8))) _Float16 f16x8;
typedef __attribute__((ext_vector_type(4))) float f32x4;

#define HD 512
#define NBSEQ 256
#define LSEQ 256
#define PREDN 96
#define SLOT 262144   // f16 elements per 512x512 matrix

// ws layout (f16):
//   [0]                : TX  = Wxh swizzled (B-frag form of y = x@Wxh^T)
//   [SLOT*k], k=1..96  : T[k] = swizzled form of A^k  (A = Whh^T)
//   [SLOT*(97+j)]      : R[2^j] row-major f16, j=0..6
//   [SLOT*104]         : Hbuf [16][256][512] f16 (chunk-end states H_c)
// total = 56 MB of d_ws (verified fits in R2).

// T-form of M: T(kk,nt,lane,j) = M[k][n], k=kk*32+(lane>>4)*8+j, n=nt*16+(lane&15)

// ---------------------------------------------------------------------------
// prep: TX (Wxh swizzled), T[1] (Whh swizzled), R[1] = A row-major (Whh^T).
// ---------------------------------------------------------------------------
__global__ __launch_bounds__(512) void prep(const float* __restrict__ Wxh,
                                            const float* __restrict__ Whh,
                                            f16* __restrict__ ws) {
    int gid = blockIdx.x * 512 + threadIdx.x;     // grid 192 -> gid < 98304
    if (gid < 65536) {
        int table = gid >> 15;
        int rem = gid & 32767;
        int kk = rem >> 11;
        int nt = (rem >> 6) & 31;
        int l = rem & 63;
        int n = nt * 16 + (l & 15);
        int k = kk * 32 + (l >> 4) * 8;
        const float* W = (table ? Whh : Wxh) + (size_t)n * HD + k;
        f16x8 v;
#pragma unroll
        for (int j = 0; j < 8; j++) v[j] = (f16)W[j];
        *reinterpret_cast<f16x8*>(ws + (size_t)gid * 8) = v;
    } else {
        int idx = gid - 65536;                    // 0..32767
        int m = idx >> 6, kc = (idx & 63) * 8;
        f16* R1 = ws + (size_t)SLOT * 97;
        f16x8 v;
#pragma unroll
        for (int j = 0; j < 8; j++) v[j] = (f16)Whh[(size_t)(kc + j) * HD + m];
        *reinterpret_cast<f16x8*>(R1 + (size_t)m * HD + kc) = v;
    }
}

// ---------------------------------------------------------------------------
// gemm_xw: xW = x @ Wxh^T  [65536,512]@[512,512] -> fp32, in-place into rec.
// (verified R1/R2)
// ---------------------------------------------------------------------------
__global__ __launch_bounds__(512, 2) void gemm_xw(const float* __restrict__ x,
                                                  const f16* __restrict__ bsw,
                                                  float* __restrict__ xw) {
    __shared__ f16 Al[2][128][40];
    __shared__ f16 Bl[2][16384];
    const int tid = threadIdx.x;
    const int w = tid >> 6, l = tid & 63;
    const size_t r0 = (size_t)blockIdx.x * 128;

    f32x4 acc[8][4];
#pragma unroll
    for (int mt = 0; mt < 8; mt++)
#pragma unroll
        for (int nt = 0; nt < 4; nt++) acc[mt][nt] = (f32x4)0.f;

    const int arow_l = l & 15;
    const int akc = (l >> 4) * 8;
    const int srow = tid >> 2, sc8 = (tid & 3) * 8;

    for (int kk = 0; kk < 16; kk++) {
        const int buf = kk & 1;
        {
            const float* src = x + (r0 + srow) * HD + kk * 32 + sc8;
            float4 f0 = *reinterpret_cast<const float4*>(src);
            float4 f1 = *reinterpret_cast<const float4*>(src + 4);
            f16x8 a;
            a[0] = (f16)f0.x; a[1] = (f16)f0.y; a[2] = (f16)f0.z; a[3] = (f16)f0.w;
            a[4] = (f16)f1.x; a[5] = (f16)f1.y; a[6] = (f16)f1.z; a[7] = (f16)f1.w;
            *reinterpret_cast<f16x8*>(&Al[buf][srow][sc8]) = a;
        }
        {
            const f16* bsrc = bsw + (size_t)kk * 16384 + tid * 8;
#pragma unroll
            for (int i = 0; i < 4; i++)
                *reinterpret_cast<f16x8*>(&Bl[buf][i * 4096 + tid * 8]) =
                    *reinterpret_cast<const f16x8*>(bsrc + i * 4096);
        }
        __syncthreads();

        f16x8 af[8];
#pragma unroll
        for (int mt = 0; mt < 8; mt++)
            af[mt] = *reinterpret_cast<const f16x8*>(&Al[buf][mt * 16 + arow_l][akc]);
#pragma unroll
        for (int nt = 0; nt < 4; nt++) {
            f16x8 bf = *reinterpret_cast<const f16x8*>(&Bl[buf][((w * 4 + nt) * 64 + l) * 8]);
#pragma unroll
            for (int mt = 0; mt < 8; mt++)
                acc[mt][nt] = __builtin_amdgcn_mfma_f32_16x16x32_f16(af[mt], bf, acc[mt][nt], 0, 0, 0);
        }
    }
#pragma unroll
    for (int mt = 0; mt < 8; mt++)
#pragma unroll
        for (int nt = 0; nt < 4; nt++)
#pragma unroll
            for (int r = 0; r < 4; r++) {
                size_t row = r0 + mt * 16 + (l >> 4) * 4 + r;
                int col = w * 64 + nt * 16 + arow_l;
                xw[row * HD + col] = acc[mt][nt][r];
            }
}

// ---------------------------------------------------------------------------
// core128: C[128,512] = A[128,512](f16 row-major) @ Y(T-form), K=512.
// ---------------------------------------------------------------------------
__device__ __forceinline__ void core128(const f16* __restrict__ Asrc,
                                        const f16* __restrict__ Y,
                                        f16 (*Al)[128][40],
                                        f32x4 (*acc)[4], int tid) {
    const int w = tid >> 6, l = tid & 63;
    const int srow = tid >> 2, sc8 = (tid & 3) * 8;
    const int arow = l & 15, ak = (l >> 4) * 8;
    for (int kk = 0; kk < 16; kk++) {
        const int buf = kk & 1;
        *reinterpret_cast<f16x8*>(&Al[buf][srow][sc8]) =
            *reinterpret_cast<const f16x8*>(Asrc + (size_t)srow * HD + kk * 32 + sc8);
        __syncthreads();
        f16x8 af[8];
#pragma unroll
        for (int mt = 0; mt < 8; mt++)
            af[mt] = *reinterpret_cast<const f16x8*>(&Al[buf][mt * 16 + arow][ak]);
#pragma unroll
        for (int nt = 0; nt < 4; nt++) {
            f16x8 b = *reinterpret_cast<const f16x8*>(Y + (size_t)(kk * 32 + w * 4 + nt) * 512 + l * 8);
#pragma unroll
            for (int mt = 0; mt < 8; mt++)
                acc[mt][nt] = __builtin_amdgcn_mfma_f32_16x16x32_f16(af[mt], b, acc[mt][nt], 0, 0, 0);
        }
    }
}

// ---------------------------------------------------------------------------
// powlevel: doubling level h (verified R2).
// ---------------------------------------------------------------------------
__global__ __launch_bounds__(512, 2) void powlevel(const f16* __restrict__ RX,
                                                   f16* __restrict__ ws,
                                                   f16* __restrict__ Rsq,
                                                   int h) {
    __shared__ f16 Al[2][128][40];
    const int tid = threadIdx.x;
    const int j0 = blockIdx.x >> 2, mtile = blockIdx.x & 3;
    const int m0 = mtile * 128;
    const f16* Y = ws + (size_t)SLOT * (1 + j0);
    f16* Tout = ws + (size_t)SLOT * (h + 1 + j0);

    f32x4 acc[8][4];
#pragma unroll
    for (int mt = 0; mt < 8; mt++)
#pragma unroll
        for (int nt = 0; nt < 4; nt++) acc[mt][nt] = (f32x4)0.f;

    core128(RX + (size_t)m0 * HD, Y, Al, acc, tid);

    const int w = tid >> 6, l = tid & 63;
    const bool doR = (1 + j0) == h;
#pragma unroll
    for (int mt = 0; mt < 8; mt++)
#pragma unroll
        for (int nt = 0; nt < 4; nt++)
#pragma unroll
            for (int r = 0; r < 4; r++) {
                int m = m0 + mt * 16 + (l >> 4) * 4 + r;
                int n = w * 64 + nt * 16 + (l & 15);
                f16 v = (f16)acc[mt][nt][r];
                size_t tix = (((size_t)(m >> 5) * 32 + (n >> 4)) * 64 +
                              (((m >> 3) & 3) * 16 + (n & 15))) * 8 + (m & 7);
                Tout[tix] = v;
                if (doR) Rsq[(size_t)m * HD + n] = v;
            }
}

// ---------------------------------------------------------------------------
// phaseA v3: local prefixes with HALF-B REGISTER RESIDENT.
// 256 WGs = 16 chunks x 16 seq-groups, M=16, 512 thr (8 waves, N=64/wave).
// breg holds T1 frags for kk=8..15 (128 VGPR); kk=0..7 streamed from L2
// with a distance-2 pipeline. Per step: 256KB L2 (was 512KB), full chip.
// ---------------------------------------------------------------------------
__global__ __launch_bounds__(512, 2) void phaseA(float* __restrict__ rec,
                                                 const f16* __restrict__ T1) {
    __shared__ f16 hb[2][16][520];
    const int tid = threadIdx.x, w = tid >> 6, l = tid & 63;
    const int c = blockIdx.x >> 4, sg = blockIdx.x & 15;
    const int s0 = sg * 16;
    {
        f16* hp = &hb[0][0][0];
        for (int i = tid; i < 16 * 520; i += 512) hp[i] = (f16)0.f;
    }
    const int arow = l & 15, ak = (l >> 4) * 8;
    const f16* bbase = T1 + (size_t)l * 8;

    // resident half: kk = 8..15
    f16x8 breg[8][4];
#pragma unroll
    for (int kk = 0; kk < 8; kk++)
#pragma unroll
        for (int nt = 0; nt < 4; nt++)
            breg[kk][nt] = *reinterpret_cast<const f16x8*>(
                bbase + (size_t)((kk + 8) * 32 + w * 4 + nt) * 512);
    __syncthreads();

    int cur = 0;
    for (int i = 0; i < 16; i++) {
        const int t = c * 16 + i;
        float xwv[4][4];
#pragma unroll
        for (int nt = 0; nt < 4; nt++)
#pragma unroll
            for (int r = 0; r < 4; r++) {
                int s = s0 + (l >> 4) * 4 + r;
                int col = w * 64 + nt * 16 + arow;
                xwv[nt][r] = rec[((size_t)s * LSEQ + t) * HD + col];
            }

        f32x4 acc[4];
#pragma unroll
        for (int nt = 0; nt < 4; nt++) acc[nt] = (f32x4)0.f;

        // streamed half pipeline: sb[q] holds frags for kk = (parity q)
        f16x8 sb[2][4];
#pragma unroll
        for (int q = 0; q < 2; q++)
#pragma unroll
            for (int nt = 0; nt < 4; nt++)
                sb[q][nt] = *reinterpret_cast<const f16x8*>(
                    bbase + (size_t)(q * 32 + w * 4 + nt) * 512);

#pragma unroll
        for (int kk = 0; kk < 8; kk++) {
            f16x8 a_r = *reinterpret_cast<const f16x8*>(&hb[cur][arow][(kk + 8) * 32 + ak]);
            f16x8 a_s = *reinterpret_cast<const f16x8*>(&hb[cur][arow][kk * 32 + ak]);
#pragma unroll
            for (int nt = 0; nt < 4; nt++)
                acc[nt] = __builtin_amdgcn_mfma_f32_16x16x32_f16(a_r, breg[kk][nt], acc[nt], 0, 0, 0);
#pragma unroll
            for (int nt = 0; nt < 4; nt++)
                acc[nt] = __builtin_amdgcn_mfma_f32_16x16x32_f16(a_s, sb[kk & 1][nt], acc[nt], 0, 0, 0);
            if (kk < 6) {
#pragma unroll
                for (int nt = 0; nt < 4; nt++)
                    sb[kk & 1][nt] = *reinterpret_cast<const f16x8*>(
                        bbase + (size_t)((kk + 2) * 32 + w * 4 + nt) * 512);
            }
        }

        const int nxt = cur ^ 1;
#pragma unroll
        for (int nt = 0; nt < 4; nt++)
#pragma unroll
            for (int r = 0; r < 4; r++) {
                int rr = (l >> 4) * 4 + r;
                int col = w * 64 + nt * 16 + arow;
                float hv = acc[nt][r] + xwv[nt][r];
                hb[nxt][rr][col] = (f16)hv;
                int s = s0 + rr;
                rec[((size_t)s * LSEQ + t) * HD + col] = hv;
            }
        __syncthreads();
        cur = nxt;
    }
}

// ---------------------------------------------------------------------------
// phaseB v3: chunk carries, same register-B treatment (T16).
// 16 WGs, M=16. H_c = H_{c-1}@A^16 + L_{c,15}.
// ---------------------------------------------------------------------------
__global__ __launch_bounds__(512, 2) void phaseB(float* __restrict__ rec,
                                                 const f16* __restrict__ T16,
                                                 f16* __restrict__ Hb) {
    __shared__ f16 hb[2][16][520];
    const int tid = threadIdx.x, w = tid >> 6, l = tid & 63;
    const int s0 = blockIdx.x * 16;
    const int arow = l & 15, ak = (l >> 4) * 8;
    const f16* bbase = T16 + (size_t)l * 8;

    f16x8 breg[8][4];
#pragma unroll
    for (int kk = 0; kk < 8; kk++)
#pragma unroll
        for (int nt = 0; nt < 4; nt++)
            breg[kk][nt] = *reinterpret_cast<const f16x8*>(
                bbase + (size_t)((kk + 8) * 32 + w * 4 + nt) * 512);

    // c = 0: H_0 = L_{0,15}
#pragma unroll
    for (int nt = 0; nt < 4; nt++)
#pragma unroll
        for (int r = 0; r < 4; r++) {
            int rr = (l >> 4) * 4 + r;
            int col = w * 64 + nt * 16 + arow;
            int s = s0 + rr;
            float v = rec[((size_t)s * LSEQ + 15) * HD + col];
            hb[0][rr][col] = (f16)v;
            Hb[(size_t)s * HD + col] = (f16)v;
        }
    __syncthreads();
    int cur = 0;
    for (int c = 1; c < 16; c++) {
        const int t = c * 16 + 15;
        float Lv[4][4];
#pragma unroll
        for (int nt = 0; nt < 4; nt++)
#pragma unroll
            for (int r = 0; r < 4; r++) {
                int s = s0 + (l >> 4) * 4 + r;
                int col = w * 64 + nt * 16 + arow;
                Lv[nt][r] = rec[((size_t)s * LSEQ + t) * HD + col];
            }
        f32x4 acc[4];
#pragma unroll
        for (int nt = 0; nt < 4; nt++) acc[nt] = (f32x4)0.f;

        f16x8 sb[2][4];
#pragma unroll
        for (int q = 0; q < 2; q++)
#pragma unroll
            for (int nt = 0; nt < 4; nt++)
                sb[q][nt] = *reinterpret_cast<const f16x8*>(
                    bbase + (size_t)(q * 32 + w * 4 + nt) * 512);

#pragma unroll
        for (int kk = 0; kk < 8; kk++) {
            f16x8 a_r = *reinterpret_cast<const f16x8*>(&hb[cur][arow][(kk + 8) * 32 + ak]);
            f16x8 a_s = *reinterpret_cast<const f16x8*>(&hb[cur][arow][kk * 32 + ak]);
#pragma unroll
            for (int nt = 0; nt < 4; nt++)
                acc[nt] = __builtin_amdgcn_mfma_f32_16x16x32_f16(a_r, breg[kk][nt], acc[nt], 0, 0, 0);
#pragma unroll
            for (int nt = 0; nt < 4; nt++)
                acc[nt] = __builtin_amdgcn_mfma_f32_16x16x32_f16(a_s, sb[kk & 1][nt], acc[nt], 0, 0, 0);
            if (kk < 6) {
#pragma unroll
                for (int nt = 0; nt < 4; nt++)
                    sb[kk & 1][nt] = *reinterpret_cast<const f16x8*>(
                        bbase + (size_t)((kk + 2) * 32 + w * 4 + nt) * 512);
            }
        }

        const int nxt = cur ^ 1;
#pragma unroll
        for (int nt = 0; nt < 4; nt++)
#pragma unroll
            for (int r = 0; r < 4; r++) {
                int rr = (l >> 4) * 4 + r;
                int col = w * 64 + nt * 16 + arow;
                float hv = acc[nt][r] + Lv[nt][r];
                hb[nxt][rr][col] = (f16)hv;
                int s = s0 + rr;
                rec[((size_t)s * LSEQ + t) * HD + col] = hv;
                Hb[((size_t)c * NBSEQ + s) * HD + col] = (f16)hv;
            }
        __syncthreads();
        cur = nxt;
    }
}

// ---------------------------------------------------------------------------
// phaseC: fill-in (verified R2). rec[s,16c+i] += Hbuf[c-1] @ A^(i+1).
// ---------------------------------------------------------------------------
__global__ __launch_bounds__(512, 2) void phaseC(float* __restrict__ rec,
                                                 const f16* __restrict__ ws,
                                                 const f16* __restrict__ Hb) {
    __shared__ f16 Al[2][128][40];
    const int tid = threadIdx.x;
    const int p = blockIdx.x >> 1, half = blockIdx.x & 1;
    const int i = p / 15, c = 1 + p % 15;
    const int m0 = half * 128;
    const f16* Y = ws + (size_t)SLOT * (i + 1);
    const f16* Asrc = Hb + ((size_t)(c - 1) * NBSEQ + m0) * HD;

    f32x4 acc[8][4];
#pragma unroll
    for (int mt = 0; mt < 8; mt++)
#pragma unroll
        for (int nt = 0; nt < 4; nt++) acc[mt][nt] = (f32x4)0.f;

    core128(Asrc, Y, Al, acc, tid);

    const int w = tid >> 6, l = tid & 63;
    const int t = c * 16 + i;
#pragma unroll
    for (int mt = 0; mt < 8; mt++)
#pragma unroll
        for (int nt = 0; nt < 4; nt++)
#pragma unroll
            for (int r = 0; r < 4; r++) {
                int s = m0 + mt * 16 + (l >> 4) * 4 + r;
                int col = w * 64 + nt * 16 + (l & 15);
                size_t a = ((size_t)s * LSEQ + t) * HD + col;
                rec[a] += acc[mt][nt][r];
            }
}

// ---------------------------------------------------------------------------
// predLN: outs[s, t-1] = LN(H_15 @ A^t), t=1..96 (verified R2).
// ---------------------------------------------------------------------------
__global__ __launch_bounds__(512, 2) void predLN(const float* __restrict__ gamma,
                                                 const float* __restrict__ beta,
                                                 const f16* __restrict__ ws,
                                                 const f16* __restrict__ Hb,
                                                 float* __restrict__ outs) {
    __shared__ f16 Al[2][128][40];
    __shared__ float psum[8][128], psq[8][128], gl[HD], bl[HD];
    const int tid = threadIdx.x;
    const int t = 1 + (blockIdx.x >> 1), half = blockIdx.x & 1;
    const int m0 = half * 128;
    gl[tid] = gamma[tid];
    bl[tid] = beta[tid];

    f32x4 acc[8][4];
#pragma unroll
    for (int mt = 0; mt < 8; mt++)
#pragma unroll
        for (int nt = 0; nt < 4; nt++) acc[mt][nt] = (f32x4)0.f;

    core128(Hb + ((size_t)15 * NBSEQ + m0) * HD, ws + (size_t)SLOT * t, Al, acc, tid);

    const int w = tid >> 6, l = tid & 63;
#pragma unroll
    for (int mt = 0; mt < 8; mt++)
#pragma unroll
        for (int r = 0; r < 4; r++) {
            int rloc = mt * 16 + (l >> 4) * 4 + r;
            float s1 = 0.f, s2 = 0.f;
#pragma unroll
            for (int nt = 0; nt < 4; nt++) {
                float v = acc[mt][nt][r];
                s1 += v; s2 += v * v;
            }
#pragma unroll
            for (int m = 8; m >= 1; m >>= 1) {
                s1 += __shfl_xor(s1, m);
                s2 += __shfl_xor(s2, m);
            }
            if ((l & 15) == 0) { psum[w][rloc] = s1; psq[w][rloc] = s2; }
        }
    __syncthreads();
#pragma unroll
    for (int mt = 0; mt < 8; mt++)
#pragma unroll
        for (int r = 0; r < 4; r++) {
            int rloc = mt * 16 + (l >> 4) * 4 + r;
            float tot = 0.f, tq = 0.f;
#pragma unroll
            for (int ww = 0; ww < 8; ww++) { tot += psum[ww][rloc]; tq += psq[ww][rloc]; }
            float mean = tot * (1.f / 512.f);
            float var = tq * (1.f / 512.f) - mean * mean;
            float rstd = rsqrtf(var + 1e-5f);
            int s = m0 + rloc;
#pragma unroll
            for (int nt = 0; nt < 4; nt++) {
                int col = w * 64 + nt * 16 + (l & 15);
                outs[((size_t)s * PREDN + (t - 1)) * HD + col] =
                    (acc[mt][nt][r] - mean) * rstd * gl[col] + bl[col];
            }
        }
}

extern "C" void kernel_launch(void* const* d_in, const int* in_sizes, int n_in,
                              void* d_out, int out_size, void* d_ws, size_t ws_size,
                              hipStream_t stream) {
    (void)in_sizes; (void)n_in; (void)out_size; (void)ws_size;
    const float* x     = (const float*)d_in[0];
    const float* Wxh   = (const float*)d_in[1];
    const float* Whh   = (const float*)d_in[2];
    const float* gamma = (const float*)d_in[3];
    const float* beta  = (const float*)d_in[4];
    float* out = (float*)d_out;
    float* outs = out + (size_t)NBSEQ * LSEQ * HD;
    f16* ws = (f16*)d_ws;

    f16* R[7];
    for (int j = 0; j < 7; j++) R[j] = ws + (size_t)SLOT * (97 + j);
    f16* Hb = ws + (size_t)SLOT * 104;

    hipLaunchKernelGGL(prep, dim3(192), dim3(512), 0, stream, Wxh, Whh, ws);
    hipLaunchKernelGGL(gemm_xw, dim3(512), dim3(512), 0, stream, x, ws, out);
    hipLaunchKernelGGL(powlevel, dim3(4),   dim3(512), 0, stream, R[0], ws, R[1], 1);
    hipLaunchKernelGGL(powlevel, dim3(8),   dim3(512), 0, stream, R[1], ws, R[2], 2);
    hipLaunchKernelGGL(powlevel, dim3(16),  dim3(512), 0, stream, R[2], ws, R[3], 4);
    hipLaunchKernelGGL(powlevel, dim3(32),  dim3(512), 0, stream, R[3], ws, R[4], 8);
    hipLaunchKernelGGL(powlevel, dim3(64),  dim3(512), 0, stream, R[4], ws, R[5], 16);
    hipLaunchKernelGGL(powlevel, dim3(128), dim3(512), 0, stream, R[5], ws, R[6], 32);
    hipLaunchKernelGGL(powlevel, dim3(128), dim3(512), 0, stream, R[6], ws, R[6], 64);
    hipLaunchKernelGGL(phaseA, dim3(256), dim3(512), 0, stream, out, ws + (size_t)SLOT * 1);
    hipLaunchKernelGGL(phaseB, dim3(16),  dim3(512), 0, stream, out, ws + (size_t)SLOT * 16, Hb);
    hipLaunchKernelGGL(phaseC, dim3(450), dim3(512), 0, stream, out, ws, Hb);
    hipLaunchKernelGGL(predLN, dim3(192), dim3(512), 0, stream, gamma, beta, ws, Hb, outs);
}